// Round 2
// baseline (285.704 us; speedup 1.0000x reference)
//
#include <hip/hip_runtime.h>
#include <hip/hip_bf16.h>

// Problem: M=4096, N=100, E=128.
// out[m,:] = relu( (softmax_n(relu([pus|pis|pss]@W1+b1)@W2+b2) . relu([C|pss]@WR+bR)) @ Wo + bo )
// d_out is FLOAT32 (reference returns f32; round-0 bf16-write left half the buffer
// zero -> absmax identical to stub. Fixed here.)

#define M_ 4096
#define N_ 100
#define E_ 128
#define R_ (M_ * N_)   // 409600 rows of (m,n)

typedef __bf16 bf16x8 __attribute__((ext_vector_type(8)));
typedef float  f32x4  __attribute__((ext_vector_type(4)));

// ---------------- weight prep: transpose + f32->bf16 ----------------
// W1t[n][k] = bf16(W1[k][n]), n<128, k<384  (49152 elems)
// WRt[n][k] = bf16(WR[k][n]), n<128, k<256  (32768 elems)
__global__ void prep_weights(const float* __restrict__ W1, const float* __restrict__ WR,
                             __bf16* __restrict__ W1t, __bf16* __restrict__ WRt) {
    int i = blockIdx.x * 256 + threadIdx.x;
    if (i < 384 * 128) {
        int n = i / 384, k = i % 384;
        W1t[i] = (__bf16)W1[k * 128 + n];
    } else {
        int j = i - 384 * 128;
        if (j < 256 * 128) {
            int n = j / 256, k = j % 256;
            WRt[j] = (__bf16)WR[k * 128 + n];
        }
    }
}

// ---------------- kernel A: scores = relu(X@W1+b1)@W2 + b2 ----------------
// X rows = (m,n) pairs (row r -> element offset r*128 in each [M,N,E] array).
// K=384: k<128 -> pus, <256 -> pis, else pss. Tile 128 rows x 128 cols, BK=64.
__global__ __launch_bounds__(256, 2) void kernelA(
    const float* __restrict__ pus, const float* __restrict__ pis, const float* __restrict__ pss,
    const __bf16* __restrict__ W1t, const float* __restrict__ b1,
    const float* __restrict__ W2, const float* __restrict__ b2,
    float* __restrict__ scores)
{
    __shared__ __align__(16) __bf16 Xs[128][64];
    __shared__ __align__(16) __bf16 Ws[128][64];
    __shared__ float part[2][128];

    const int tid  = threadIdx.x;
    const int lane = tid & 63;
    const int wid  = tid >> 6;
    const int wr = wid >> 1, wc = wid & 1;      // wave quadrant (rows, cols)
    const long rowbase = (long)blockIdx.x * 128;

    f32x4 acc[4][4] = {};

    for (int kt = 0; kt < 6; ++kt) {
        const int k0 = kt * 64;
        const float* __restrict__ src = (kt < 2) ? pus : (kt < 4) ? pis : pss;
        const int colbase = k0 & 127;

        __syncthreads();  // previous iteration's reads done before overwrite
        // stage X tile: 128 rows x 64 k (f32 -> bf16), 2048 x 16B-src chunks
        #pragma unroll
        for (int i = 0; i < 8; ++i) {
            int c  = tid + 256 * i;
            int r  = c >> 4;               // 0..127
            int k4 = (c & 15) << 2;        // float index 0..60
            const float4 v = *reinterpret_cast<const float4*>(
                src + (rowbase + r) * 128 + colbase + k4);
            int blk  = k4 >> 3;            // 16B-block index 0..7
            int phys = ((blk ^ (r & 7)) << 3) + (k4 & 7);  // XOR swizzle
            union { __bf16 h[4]; uint2 u; } tw;
            tw.h[0] = (__bf16)v.x; tw.h[1] = (__bf16)v.y;
            tw.h[2] = (__bf16)v.z; tw.h[3] = (__bf16)v.w;
            *reinterpret_cast<uint2*>(&Xs[r][phys]) = tw.u;
        }
        // stage W1t slab: 128 n x 64 k (bf16 copy), 1024 x 16B chunks
        #pragma unroll
        for (int i = 0; i < 4; ++i) {
            int c  = tid + 256 * i;
            int n  = c >> 3;               // 0..127
            int kb = c & 7;                // 16B block
            uint4 v = *reinterpret_cast<const uint4*>(W1t + n * 384 + k0 + (kb << 3));
            *reinterpret_cast<uint4*>(&Ws[n][(kb ^ (n & 7)) << 3]) = v;
        }
        __syncthreads();

        #pragma unroll
        for (int ks = 0; ks < 2; ++ks) {
            const int g = lane >> 4;
            const int kblk = (ks << 2) + g;
            bf16x8 af[4], bfr[4];
            #pragma unroll
            for (int a = 0; a < 4; ++a) {
                int rr = wr * 64 + a * 16 + (lane & 15);
                af[a] = *reinterpret_cast<const bf16x8*>(&Xs[rr][(kblk ^ (rr & 7)) << 3]);
            }
            #pragma unroll
            for (int b = 0; b < 4; ++b) {
                int nn = wc * 64 + b * 16 + (lane & 15);
                bfr[b] = *reinterpret_cast<const bf16x8*>(&Ws[nn][(kblk ^ (nn & 7)) << 3]);
            }
            #pragma unroll
            for (int a = 0; a < 4; ++a)
                #pragma unroll
                for (int b = 0; b < 4; ++b)
                    acc[a][b] = __builtin_amdgcn_mfma_f32_16x16x32_bf16(
                        af[a], bfr[b], acc[a][b], 0, 0, 0);
        }
    }

    // epilogue: score_row = sum_col relu(h + b1[col]) * W2[col]
    float w2v[4], b1v[4];
    #pragma unroll
    for (int b = 0; b < 4; ++b) {
        int col = wc * 64 + b * 16 + (lane & 15);
        w2v[b] = W2[col];
        b1v[b] = b1[col];
    }
    #pragma unroll
    for (int a = 0; a < 4; ++a) {
        #pragma unroll
        for (int r = 0; r < 4; ++r) {
            float ps = 0.f;
            #pragma unroll
            for (int b = 0; b < 4; ++b) {
                float h = fmaxf(acc[a][b][r] + b1v[b], 0.f);
                ps += h * w2v[b];
            }
            ps += __shfl_xor(ps, 1);
            ps += __shfl_xor(ps, 2);
            ps += __shfl_xor(ps, 4);
            ps += __shfl_xor(ps, 8);
            if ((lane & 15) == 0) {
                int row = wr * 64 + a * 16 + ((lane >> 4) << 2) + r;
                part[wc][row] = ps;
            }
        }
    }
    __syncthreads();
    if (tid < 128)
        scores[rowbase + tid] = part[0][tid] + part[1][tid] + b2[0];
}

// ---------------- kernel B: softmax + v-GEMM + pooling + lout ----------------
// One block per m. Rows = paths n (100 real, padded to 128). K=256: k<128 -> C else pss.
__global__ __launch_bounds__(256, 2) void kernelB(
    const float* __restrict__ Cc, const float* __restrict__ pss,
    const __bf16* __restrict__ WRt, const float* __restrict__ bR,
    const float* __restrict__ Wo, const float* __restrict__ bo,
    const float* __restrict__ scores, float* __restrict__ out)
{
    __shared__ __align__(16) __bf16 Xs[128][64];
    __shared__ __align__(16) __bf16 Ws[128][64];
    __shared__ float wLDS[128];
    __shared__ float pairp[2][128];
    __shared__ float pairLDS[128];

    const int tid  = threadIdx.x;
    const int lane = tid & 63;
    const int wid  = tid >> 6;
    const int wr = wid >> 1, wc = wid & 1;
    const int m = blockIdx.x;
    const long base = (long)m * N_;

    // softmax over the m's 100 scores (wave 0)
    if (wid == 0) {
        float s0 = (lane < 100) ? scores[base + lane] : -3e38f;
        float s1 = (lane + 64 < 100) ? scores[base + lane + 64] : -3e38f;
        float mx = fmaxf(s0, s1);
        #pragma unroll
        for (int off = 1; off < 64; off <<= 1) mx = fmaxf(mx, __shfl_xor(mx, off));
        float e0 = (lane < 100) ? __expf(s0 - mx) : 0.f;
        float e1 = (lane + 64 < 100) ? __expf(s1 - mx) : 0.f;
        float sum = e0 + e1;
        #pragma unroll
        for (int off = 1; off < 64; off <<= 1) sum += __shfl_xor(sum, off);
        float inv = 1.f / sum;
        wLDS[lane]      = e0 * inv;
        wLDS[lane + 64] = e1 * inv;
    }

    f32x4 acc[4][4] = {};

    for (int kt = 0; kt < 4; ++kt) {
        const int k0 = kt * 64;
        const float* __restrict__ src = (kt < 2) ? Cc : pss;
        const int colbase = k0 & 127;

        __syncthreads();
        #pragma unroll
        for (int i = 0; i < 8; ++i) {
            int c  = tid + 256 * i;
            int r  = c >> 4;
            int k4 = (c & 15) << 2;
            float4 v = {0.f, 0.f, 0.f, 0.f};
            if (r < N_)
                v = *reinterpret_cast<const float4*>(src + (base + r) * 128 + colbase + k4);
            int blk  = k4 >> 3;
            int phys = ((blk ^ (r & 7)) << 3) + (k4 & 7);
            union { __bf16 h[4]; uint2 u; } tw;
            tw.h[0] = (__bf16)v.x; tw.h[1] = (__bf16)v.y;
            tw.h[2] = (__bf16)v.z; tw.h[3] = (__bf16)v.w;
            *reinterpret_cast<uint2*>(&Xs[r][phys]) = tw.u;
        }
        #pragma unroll
        for (int i = 0; i < 4; ++i) {
            int c  = tid + 256 * i;
            int n  = c >> 3;
            int kb = c & 7;
            uint4 v = *reinterpret_cast<const uint4*>(WRt + n * 256 + k0 + (kb << 3));
            *reinterpret_cast<uint4*>(&Ws[n][(kb ^ (n & 7)) << 3]) = v;
        }
        __syncthreads();

        #pragma unroll
        for (int ks = 0; ks < 2; ++ks) {
            const int g = lane >> 4;
            const int kblk = (ks << 2) + g;
            bf16x8 af[4], bfr[4];
            #pragma unroll
            for (int a = 0; a < 4; ++a) {
                int rr = wr * 64 + a * 16 + (lane & 15);
                af[a] = *reinterpret_cast<const bf16x8*>(&Xs[rr][(kblk ^ (rr & 7)) << 3]);
            }
            #pragma unroll
            for (int b = 0; b < 4; ++b) {
                int nn = wc * 64 + b * 16 + (lane & 15);
                bfr[b] = *reinterpret_cast<const bf16x8*>(&Ws[nn][(kblk ^ (nn & 7)) << 3]);
            }
            #pragma unroll
            for (int a = 0; a < 4; ++a)
                #pragma unroll
                for (int b = 0; b < 4; ++b)
                    acc[a][b] = __builtin_amdgcn_mfma_f32_16x16x32_bf16(
                        af[a], bfr[b], acc[a][b], 0, 0, 0);
        }
    }

    // epilogue: pair[col] = sum_rows w[row] * relu(v + bR[col])
    float bRv[4];
    #pragma unroll
    for (int b = 0; b < 4; ++b)
        bRv[b] = bR[wc * 64 + b * 16 + (lane & 15)];

    float psum[4] = {0.f, 0.f, 0.f, 0.f};
    const int g = lane >> 4;
    #pragma unroll
    for (int a = 0; a < 4; ++a) {
        #pragma unroll
        for (int r = 0; r < 4; ++r) {
            int row = wr * 64 + a * 16 + g * 4 + r;
            float wgt = wLDS[row];
            #pragma unroll
            for (int b = 0; b < 4; ++b) {
                float v = fmaxf(acc[a][b][r] + bRv[b], 0.f);
                psum[b] += wgt * v;
            }
        }
    }
    #pragma unroll
    for (int b = 0; b < 4; ++b) {
        psum[b] += __shfl_xor(psum[b], 16);
        psum[b] += __shfl_xor(psum[b], 32);
    }
    if (lane < 16) {
        #pragma unroll
        for (int b = 0; b < 4; ++b)
            pairp[wr][wc * 64 + b * 16 + lane] = psum[b];
    }
    __syncthreads();
    if (tid < 128) pairLDS[tid] = pairp[0][tid] + pairp[1][tid];
    __syncthreads();

    // lout: out[m][e] = relu(sum_k pair[k] * Wo[k][e] + bo[e])
    if (tid < 128) {
        float o = bo[tid];
        #pragma unroll 8
        for (int k = 0; k < 128; ++k)
            o += pairLDS[k] * Wo[k * 128 + tid];
        o = fmaxf(o, 0.f);
        out[(long)m * 128 + tid] = o;
    }
}

extern "C" void kernel_launch(void* const* d_in, const int* in_sizes, int n_in,
                              void* d_out, int out_size, void* d_ws, size_t ws_size,
                              hipStream_t stream) {
    const float* pus = (const float*)d_in[2];
    const float* pis = (const float*)d_in[3];
    const float* pss = (const float*)d_in[4];
    const float* C   = (const float*)d_in[5];
    const float* W1  = (const float*)d_in[6];
    const float* b1  = (const float*)d_in[7];
    const float* W2  = (const float*)d_in[8];
    const float* b2  = (const float*)d_in[9];
    const float* WR  = (const float*)d_in[10];
    const float* bR  = (const float*)d_in[11];
    const float* Wo  = (const float*)d_in[12];
    const float* bo  = (const float*)d_in[13];
    (void)in_sizes; (void)n_in; (void)ws_size;

    // workspace: scores f32[R] | W1t bf16[128*384] | WRt bf16[128*256]
    float*  scores = (float*)d_ws;
    __bf16* W1t = (__bf16*)((char*)d_ws + (size_t)R_ * 4);
    __bf16* WRt = W1t + 384 * 128;

    prep_weights<<<320, 256, 0, stream>>>(W1, WR, W1t, WRt);
    kernelA<<<R_ / 128, 256, 0, stream>>>(pus, pis, pss, W1t, b1, W2, b2, scores);
    kernelB<<<M_, 256, 0, stream>>>(C, pss, WRt, bR, Wo, bo, scores,
                                    (float*)d_out);
}

// Round 3
// 284.861 us; speedup vs baseline: 1.0030x; 1.0030x over previous
//
#include <hip/hip_runtime.h>
#include <hip/hip_bf16.h>

// Fused: out[m,:] = relu( (softmax_n(relu([pus|pis|pss]@W1+b1)@W2+b2) .
//                          relu([C|pss]@WR+bR)) @ Wo + bo )
// One block per m (rows = 100 paths padded to 128). 10 K-steps of 64:
// steps 0-5 = scores-GEMM (pus,pus,pis,pis,pss,pss vs W1t), mid-epilogue softmax,
// steps 6-9 = value-GEMM (C,C,pss,pss vs WRt), epilogue pooling + lout.
// Pipeline: X reg-prefetch 1 step ahead; W via global_load_lds (pre-swizzled src,
// linear LDS dest); raw s_barrier + counted vmcnt(8) keeps prefetch in flight.

#define M_ 4096
#define N_ 100
#define E_ 128

typedef __bf16 bf16x8 __attribute__((ext_vector_type(8)));
typedef float  f32x4  __attribute__((ext_vector_type(4)));

#define GLOAD_LDS16(g, l)                                                    \
  __builtin_amdgcn_global_load_lds(                                          \
      (const __attribute__((address_space(1))) void*)(g),                    \
      (__attribute__((address_space(3))) void*)(l), 16, 0, 0)

// W1t[n][k] = bf16(W1[k][n]) (n<128,k<384); WRt[n][k] = bf16(WR[k][n]) (k<256)
__global__ void prep_weights(const float* __restrict__ W1, const float* __restrict__ WR,
                             __bf16* __restrict__ W1t, __bf16* __restrict__ WRt) {
    int i = blockIdx.x * 256 + threadIdx.x;
    if (i < 384 * 128) {
        int n = i / 384, k = i % 384;
        W1t[i] = (__bf16)W1[k * 128 + n];
    } else {
        int j = i - 384 * 128;
        if (j < 256 * 128) {
            int n = j / 256, k = j % 256;
            WRt[j] = (__bf16)WR[k * 128 + n];
        }
    }
}

__global__ __launch_bounds__(256, 3) void fused(
    const float* __restrict__ pus, const float* __restrict__ pis,
    const float* __restrict__ pss, const float* __restrict__ Cc,
    const __bf16* __restrict__ W1t, const float* __restrict__ b1,
    const float* __restrict__ W2, const float* __restrict__ b2,
    const __bf16* __restrict__ WRt, const float* __restrict__ bR,
    const float* __restrict__ Wo, const float* __restrict__ bo,
    float* __restrict__ out)
{
    __shared__ __align__(16) __bf16 Xs[128][64];
    __shared__ __align__(16) __bf16 Ws[128][64];
    __shared__ float part[2][128];
    __shared__ float sLDS[128];
    __shared__ float wLDS[128];
    __shared__ float pairLDS[128];

    const int tid  = threadIdx.x;
    const int lane = tid & 63;
    const int wid  = tid >> 6;
    const int wr = wid >> 1, wc = wid & 1;
    const int m = blockIdx.x;
    const long base = (long)m * (N_ * E_);

    float4 xv[8];

    // X prefetch: 8 float4 per thread; padding rows clamp to row 99 (their
    // products are masked later: softmax mask / weight=0).
    auto prefetchX = [&](const float* __restrict__ src, int colbase) {
        #pragma unroll
        for (int i = 0; i < 8; ++i) {
            int c  = tid + 256 * i;
            int r  = c >> 4;
            int rc = (r < N_) ? r : (N_ - 1);
            int k4 = (c & 15) << 2;
            xv[i] = *reinterpret_cast<const float4*>(src + base + (long)rc * E_ + colbase + k4);
        }
    };
    // cvt f32->bf16 + XOR-swizzled ds_write (same layout as verified r2 kernel)
    auto writeX = [&]() {
        #pragma unroll
        for (int i = 0; i < 8; ++i) {
            int c  = tid + 256 * i;
            int r  = c >> 4;
            int k4 = (c & 15) << 2;
            int blk  = k4 >> 3;
            int phys = ((blk ^ (r & 7)) << 3) + (k4 & 7);
            union { __bf16 h[4]; uint2 u; } tw;
            tw.h[0] = (__bf16)xv[i].x; tw.h[1] = (__bf16)xv[i].y;
            tw.h[2] = (__bf16)xv[i].z; tw.h[3] = (__bf16)xv[i].w;
            *reinterpret_cast<uint2*>(&Xs[r][phys]) = tw.u;
        }
    };
    // W stage: linear LDS dest (wave-uniform base + lane*16), inverse-swizzled
    // global source so reads with (kblk ^ (n&7)) see the right data.
    auto stageW = [&](const __bf16* __restrict__ Wt, int wstride, int k0) {
        #pragma unroll
        for (int j = 0; j < 4; ++j) {
            int chunk = wid * 4 + j;               // 16 x 1KB chunks
            int n  = chunk * 8 + (lane >> 3);      // row 0..127
            int kb = (lane & 7) ^ (n & 7);         // pre-swizzled source block
            GLOAD_LDS16(Wt + n * wstride + k0 + (kb << 3), &Ws[chunk * 8][0]);
        }
    };

    f32x4 acc[4][4] = {};

    prefetchX(pus, 0);

    #pragma unroll
    for (int s = 0; s < 10; ++s) {
        // per-wave VMEM queue this step: [W x4, Xnext x8]
        if (s < 6) stageW(W1t, 384, s * 64);
        else       stageW(WRt, 256, (s - 6) * 64);
        writeX();   // compiler waits the xv loads (vmcnt<=4) before cvt
        if (s < 9) {
            const float* nsrc = (s + 1 < 2) ? pus : (s + 1 < 4) ? pis
                              : (s + 1 < 6) ? pss : (s + 1 < 8) ? Cc : pss;
            prefetchX(nsrc, ((s + 1) & 1) << 6);
        }
        asm volatile("s_waitcnt lgkmcnt(0)" ::: "memory");   // my ds_writes done
        if (s == 9) { asm volatile("s_waitcnt vmcnt(0)" ::: "memory"); }
        else        { asm volatile("s_waitcnt vmcnt(8)" ::: "memory"); } // W done, X stays in flight
        __builtin_amdgcn_s_barrier();
        asm volatile("" ::: "memory");

        #pragma unroll
        for (int ks = 0; ks < 2; ++ks) {
            const int g = lane >> 4;
            const int kblk = (ks << 2) + g;
            bf16x8 af[4], bfr[4];
            #pragma unroll
            for (int a = 0; a < 4; ++a) {
                int rr = wr * 64 + a * 16 + (lane & 15);
                af[a] = *reinterpret_cast<const bf16x8*>(&Xs[rr][(kblk ^ (rr & 7)) << 3]);
            }
            #pragma unroll
            for (int b = 0; b < 4; ++b) {
                int nn = wc * 64 + b * 16 + (lane & 15);
                bfr[b] = *reinterpret_cast<const bf16x8*>(&Ws[nn][(kblk ^ (nn & 7)) << 3]);
            }
            #pragma unroll
            for (int a = 0; a < 4; ++a)
                #pragma unroll
                for (int b = 0; b < 4; ++b)
                    acc[a][b] = __builtin_amdgcn_mfma_f32_16x16x32_bf16(
                        af[a], bfr[b], acc[a][b], 0, 0, 0);
        }
        __builtin_amdgcn_s_barrier();
        asm volatile("" ::: "memory");

        if (s == 5) {
            // ---- epilogue A: scores + softmax (verified r2 code) ----
            float w2v[4], b1v[4];
            #pragma unroll
            for (int b = 0; b < 4; ++b) {
                int col = wc * 64 + b * 16 + (lane & 15);
                w2v[b] = W2[col]; b1v[b] = b1[col];
            }
            #pragma unroll
            for (int a = 0; a < 4; ++a) {
                #pragma unroll
                for (int r = 0; r < 4; ++r) {
                    float ps = 0.f;
                    #pragma unroll
                    for (int b = 0; b < 4; ++b) {
                        float h = fmaxf(acc[a][b][r] + b1v[b], 0.f);
                        ps += h * w2v[b];
                    }
                    ps += __shfl_xor(ps, 1);
                    ps += __shfl_xor(ps, 2);
                    ps += __shfl_xor(ps, 4);
                    ps += __shfl_xor(ps, 8);
                    if ((lane & 15) == 0) {
                        int row = wr * 64 + a * 16 + ((lane >> 4) << 2) + r;
                        part[wc][row] = ps;
                    }
                }
            }
            __syncthreads();
            if (tid < 128) sLDS[tid] = part[0][tid] + part[1][tid] + b2[0];
            __syncthreads();
            if (wid == 0) {
                float s0 = (lane < N_) ? sLDS[lane] : -3e38f;
                float s1 = (lane + 64 < N_) ? sLDS[lane + 64] : -3e38f;
                float mx = fmaxf(s0, s1);
                #pragma unroll
                for (int off = 1; off < 64; off <<= 1) mx = fmaxf(mx, __shfl_xor(mx, off));
                float e0 = (lane < N_) ? __expf(s0 - mx) : 0.f;
                float e1 = (lane + 64 < N_) ? __expf(s1 - mx) : 0.f;
                float sum = e0 + e1;
                #pragma unroll
                for (int off = 1; off < 64; off <<= 1) sum += __shfl_xor(sum, off);
                float inv = 1.f / sum;
                wLDS[lane]      = e0 * inv;
                wLDS[lane + 64] = e1 * inv;
            }
            #pragma unroll
            for (int a = 0; a < 4; ++a)
                #pragma unroll
                for (int b = 0; b < 4; ++b)
                    #pragma unroll
                    for (int q = 0; q < 4; ++q)
                        acc[a][b][q] = 0.f;
        }
    }

    // ---- epilogue B: weighted pooling + lout (verified r2 code) ----
    {
        float bRv[4];
        #pragma unroll
        for (int b = 0; b < 4; ++b)
            bRv[b] = bR[wc * 64 + b * 16 + (lane & 15)];
        float psum[4] = {0.f, 0.f, 0.f, 0.f};
        const int g = lane >> 4;
        #pragma unroll
        for (int a = 0; a < 4; ++a) {
            #pragma unroll
            for (int r = 0; r < 4; ++r) {
                int row = wr * 64 + a * 16 + g * 4 + r;
                float wgt = wLDS[row];
                #pragma unroll
                for (int b = 0; b < 4; ++b) {
                    float v = fmaxf(acc[a][b][r] + bRv[b], 0.f);
                    psum[b] += wgt * v;
                }
            }
        }
        #pragma unroll
        for (int b = 0; b < 4; ++b) {
            psum[b] += __shfl_xor(psum[b], 16);
            psum[b] += __shfl_xor(psum[b], 32);
        }
        if (lane < 16) {
            #pragma unroll
            for (int b = 0; b < 4; ++b)
                part[wr][wc * 64 + b * 16 + lane] = psum[b];
        }
        __syncthreads();
        if (tid < 128) pairLDS[tid] = part[0][tid] + part[1][tid];
        __syncthreads();
        if (tid < 128) {
            float o = bo[tid];
            #pragma unroll 8
            for (int k = 0; k < 128; ++k)
                o += pairLDS[k] * Wo[k * 128 + tid];
            out[(long)m * 128 + tid] = fmaxf(o, 0.f);
        }
    }
}

extern "C" void kernel_launch(void* const* d_in, const int* in_sizes, int n_in,
                              void* d_out, int out_size, void* d_ws, size_t ws_size,
                              hipStream_t stream) {
    const float* pus = (const float*)d_in[2];
    const float* pis = (const float*)d_in[3];
    const float* pss = (const float*)d_in[4];
    const float* C   = (const float*)d_in[5];
    const float* W1  = (const float*)d_in[6];
    const float* b1  = (const float*)d_in[7];
    const float* W2  = (const float*)d_in[8];
    const float* b2  = (const float*)d_in[9];
    const float* WR  = (const float*)d_in[10];
    const float* bR  = (const float*)d_in[11];
    const float* Wo  = (const float*)d_in[12];
    const float* bo  = (const float*)d_in[13];
    (void)in_sizes; (void)n_in; (void)ws_size;

    // workspace: W1t bf16[128*384] | WRt bf16[128*256]
    __bf16* W1t = (__bf16*)d_ws;
    __bf16* WRt = W1t + 384 * 128;

    prep_weights<<<320, 256, 0, stream>>>(W1, WR, W1t, WRt);
    fused<<<M_, 256, 0, stream>>>(pus, pis, pss, C, W1t, b1, W2, b2,
                                  WRt, bR, Wo, bo, (float*)d_out);
}

// Round 4
// 222.013 us; speedup vs baseline: 1.2869x; 1.2831x over previous
//
#include <hip/hip_runtime.h>
#include <hip/hip_bf16.h>

// Fused: out[m,:] = relu( (softmax_n(relu([pus|pis|pss]@W1+b1)@W2+b2) .
//                          relu([C|pss]@WR+bR)) @ Wo + bo )
// One block per m (rows = 100 paths padded to 128). 10 K-steps of 64.
// Round-4 structure: double-buffered LDS (1 barrier/step), depth-2 X reg
// prefetch, W via global_load_lds, counted vmcnt(8) (vmcnt(0) tail),
// launch_bounds(256,2) to avoid the round-3 VGPR spill (227MB scratch writes).

#define M_ 4096
#define N_ 100
#define E_ 128

typedef __bf16 bf16x8 __attribute__((ext_vector_type(8)));
typedef float  f32x4  __attribute__((ext_vector_type(4)));

#define GLOAD_LDS16(g, l)                                                    \
  __builtin_amdgcn_global_load_lds(                                          \
      (const __attribute__((address_space(1))) void*)(g),                    \
      (__attribute__((address_space(3))) void*)(l), 16, 0, 0)

// W1t[n][k] = bf16(W1[k][n]) (n<128,k<384); WRt[n][k] = bf16(WR[k][n]) (k<256)
__global__ void prep_weights(const float* __restrict__ W1, const float* __restrict__ WR,
                             __bf16* __restrict__ W1t, __bf16* __restrict__ WRt) {
    int i = blockIdx.x * 256 + threadIdx.x;
    if (i < 384 * 128) {
        int n = i / 384, k = i % 384;
        W1t[i] = (__bf16)W1[k * 128 + n];
    } else {
        int j = i - 384 * 128;
        if (j < 256 * 128) {
            int n = j / 256, k = j % 256;
            WRt[j] = (__bf16)WR[k * 128 + n];
        }
    }
}

__global__ __launch_bounds__(256, 2) void fused(
    const float* __restrict__ pus, const float* __restrict__ pis,
    const float* __restrict__ pss, const float* __restrict__ Cc,
    const __bf16* __restrict__ W1t, const float* __restrict__ b1,
    const float* __restrict__ W2, const float* __restrict__ b2,
    const __bf16* __restrict__ WRt, const float* __restrict__ bR,
    const float* __restrict__ Wo, const float* __restrict__ bo,
    float* __restrict__ out)
{
    __shared__ __align__(16) __bf16 Xs[2][128][64];
    __shared__ __align__(16) __bf16 Ws[2][128][64];
    __shared__ float part[2][128];
    __shared__ float sLDS[128];
    __shared__ float wLDS[128];
    __shared__ float pairLDS[128];

    const int tid  = threadIdx.x;
    const int lane = tid & 63;
    const int wid  = tid >> 6;
    const int wr = wid >> 1, wc = wid & 1;
    const int m = blockIdx.x;
    const long base = (long)m * (N_ * E_);

    // hoisted small operands (keeps the main-loop vmcnt queue clean)
    float w2v[4], b1v[4], bRv[4];
    #pragma unroll
    for (int b = 0; b < 4; ++b) {
        int col = wc * 64 + b * 16 + (lane & 15);
        w2v[b] = W2[col]; b1v[b] = b1[col]; bRv[b] = bR[col];
    }
    const float b2v = b2[0];

    float4 xvE[8], xvO[8];

    // X fetch for step `step`: 8 float4/thread; pad rows clamp to row 99
    // (masked later by softmax mask / weight=0).
    auto fetchX = [&](float4 (&xv)[8], int step) {
        const float* __restrict__ src =
            (step < 2) ? pus : (step < 4) ? pis : (step < 6) ? pss
          : (step < 8) ? Cc : pss;
        const int colbase = (step & 1) << 6;
        #pragma unroll
        for (int i = 0; i < 8; ++i) {
            int c  = tid + 256 * i;
            int r  = c >> 4;
            int rc = (r < N_) ? r : (N_ - 1);
            int k4 = (c & 15) << 2;
            xv[i] = *reinterpret_cast<const float4*>(
                src + base + (long)rc * E_ + colbase + k4);
        }
    };
    // cvt f32->bf16 + XOR-swizzled ds_write into buffer `buf`
    auto writeX = [&](float4 (&xv)[8], int buf) {
        #pragma unroll
        for (int i = 0; i < 8; ++i) {
            int c  = tid + 256 * i;
            int r  = c >> 4;
            int k4 = (c & 15) << 2;
            int blk  = k4 >> 3;
            int phys = ((blk ^ (r & 7)) << 3) + (k4 & 7);
            union { __bf16 h[4]; uint2 u; } tw;
            tw.h[0] = (__bf16)xv[i].x; tw.h[1] = (__bf16)xv[i].y;
            tw.h[2] = (__bf16)xv[i].z; tw.h[3] = (__bf16)xv[i].w;
            *reinterpret_cast<uint2*>(&Xs[buf][r][phys]) = tw.u;
        }
    };
    // W stage: linear LDS dest, inverse-swizzled global source (rule 21)
    auto stageW = [&](int step, int buf) {
        const __bf16* __restrict__ Wt = (step < 6) ? W1t : WRt;
        const int wstride = (step < 6) ? 384 : 256;
        const int k0 = (step < 6) ? step * 64 : (step - 6) * 64;
        #pragma unroll
        for (int j = 0; j < 4; ++j) {
            int chunk = wid * 4 + j;               // 16 x 1KB chunks
            int n  = chunk * 8 + (lane >> 3);
            int kb = (lane & 7) ^ (n & 7);
            GLOAD_LDS16(Wt + n * wstride + k0 + (kb << 3), &Ws[buf][chunk * 8][0]);
        }
    };

    f32x4 acc[4][4] = {};

    // ---- prologue: fill buf0, X(1) + X(2) in regs/flight ----
    fetchX(xvE, 0);
    fetchX(xvO, 1);
    stageW(0, 0);
    __builtin_amdgcn_sched_barrier(0);
    writeX(xvE, 0);          // compiler waits xvE loads
    fetchX(xvE, 2);
    __builtin_amdgcn_sched_barrier(0);
    asm volatile("s_waitcnt lgkmcnt(0)" ::: "memory");
    asm volatile("s_waitcnt vmcnt(8)" ::: "memory");  // drains W(0); X(2) in flight
    __builtin_amdgcn_s_barrier();

    #pragma unroll
    for (int s = 0; s < 10; ++s) {
        const int cur = s & 1;

        // issue next-step memory first; MFMA below hides its latency
        if (s < 9) {
            stageW(s + 1, cur ^ 1);
            __builtin_amdgcn_sched_barrier(0);   // pin W-before-X issue order
            if (((s + 1) & 1) == 0) {
                writeX(xvE, cur ^ 1);
                if (s + 3 < 10) fetchX(xvE, s + 3);
            } else {
                writeX(xvO, cur ^ 1);
                if (s + 3 < 10) fetchX(xvO, s + 3);
            }
            __builtin_amdgcn_sched_barrier(0);
        }

        // fragments + MFMA on buffer `cur`
        #pragma unroll
        for (int ks = 0; ks < 2; ++ks) {
            const int g = lane >> 4;
            const int kblk = (ks << 2) + g;
            bf16x8 af[4], bfr[4];
            #pragma unroll
            for (int a = 0; a < 4; ++a) {
                int rr = wr * 64 + a * 16 + (lane & 15);
                af[a] = *reinterpret_cast<const bf16x8*>(&Xs[cur][rr][(kblk ^ (rr & 7)) << 3]);
            }
            #pragma unroll
            for (int b = 0; b < 4; ++b) {
                int nn = wc * 64 + b * 16 + (lane & 15);
                bfr[b] = *reinterpret_cast<const bf16x8*>(&Ws[cur][nn][(kblk ^ (nn & 7)) << 3]);
            }
            #pragma unroll
            for (int a = 0; a < 4; ++a)
                #pragma unroll
                for (int b = 0; b < 4; ++b)
                    acc[a][b] = __builtin_amdgcn_mfma_f32_16x16x32_bf16(
                        af[a], bfr[b], acc[a][b], 0, 0, 0);
        }

        if (s == 5) {
            // ---- epilogue A: scores + softmax (raw barriers: no vmcnt drain) ----
            #pragma unroll
            for (int a = 0; a < 4; ++a) {
                #pragma unroll
                for (int r = 0; r < 4; ++r) {
                    float ps = 0.f;
                    #pragma unroll
                    for (int b = 0; b < 4; ++b) {
                        float h = fmaxf(acc[a][b][r] + b1v[b], 0.f);
                        ps += h * w2v[b];
                    }
                    ps += __shfl_xor(ps, 1);
                    ps += __shfl_xor(ps, 2);
                    ps += __shfl_xor(ps, 4);
                    ps += __shfl_xor(ps, 8);
                    if ((lane & 15) == 0) {
                        int row = wr * 64 + a * 16 + ((lane >> 4) << 2) + r;
                        part[wc][row] = ps;
                    }
                }
            }
            asm volatile("s_waitcnt lgkmcnt(0)" ::: "memory");
            __builtin_amdgcn_s_barrier();
            if (tid < 128) sLDS[tid] = part[0][tid] + part[1][tid] + b2v;
            asm volatile("s_waitcnt lgkmcnt(0)" ::: "memory");
            __builtin_amdgcn_s_barrier();
            if (wid == 0) {
                float s0 = (lane < N_) ? sLDS[lane] : -3e38f;
                float s1 = (lane + 64 < N_) ? sLDS[lane + 64] : -3e38f;
                float mx = fmaxf(s0, s1);
                #pragma unroll
                for (int off = 1; off < 64; off <<= 1) mx = fmaxf(mx, __shfl_xor(mx, off));
                float e0 = (lane < N_) ? __expf(s0 - mx) : 0.f;
                float e1 = (lane + 64 < N_) ? __expf(s1 - mx) : 0.f;
                float sum = e0 + e1;
                #pragma unroll
                for (int off = 1; off < 64; off <<= 1) sum += __shfl_xor(sum, off);
                float inv = 1.f / sum;
                wLDS[lane]      = e0 * inv;
                wLDS[lane + 64] = e1 * inv;
            }
            // wLDS visibility: iter-end lgkm(0)+barrier below
            #pragma unroll
            for (int a = 0; a < 4; ++a)
                #pragma unroll
                for (int b = 0; b < 4; ++b)
                    #pragma unroll
                    for (int q = 0; q < 4; ++q)
                        acc[a][b][q] = 0.f;
        }

        asm volatile("s_waitcnt lgkmcnt(0)" ::: "memory");
        if (s < 7) asm volatile("s_waitcnt vmcnt(8)" ::: "memory");  // W done, X in flight
        else       asm volatile("s_waitcnt vmcnt(0)" ::: "memory");  // tail: W youngest
        __builtin_amdgcn_s_barrier();
    }

    // ---- epilogue B: weighted pooling + lout ----
    {
        float psum[4] = {0.f, 0.f, 0.f, 0.f};
        const int g = lane >> 4;
        #pragma unroll
        for (int a = 0; a < 4; ++a) {
            #pragma unroll
            for (int r = 0; r < 4; ++r) {
                int row = wr * 64 + a * 16 + g * 4 + r;
                float wgt = wLDS[row];
                #pragma unroll
                for (int b = 0; b < 4; ++b) {
                    float v = fmaxf(acc[a][b][r] + bRv[b], 0.f);
                    psum[b] += wgt * v;
                }
            }
        }
        #pragma unroll
        for (int b = 0; b < 4; ++b) {
            psum[b] += __shfl_xor(psum[b], 16);
            psum[b] += __shfl_xor(psum[b], 32);
        }
        if (lane < 16) {
            #pragma unroll
            for (int b = 0; b < 4; ++b)
                part[wr][wc * 64 + b * 16 + lane] = psum[b];
        }
        __syncthreads();
        if (tid < 128) pairLDS[tid] = part[0][tid] + part[1][tid];
        __syncthreads();
        if (tid < 128) {
            float o = bo[tid];
            #pragma unroll 8
            for (int k = 0; k < 128; ++k)
                o += pairLDS[k] * Wo[k * 128 + tid];
            out[(long)m * 128 + tid] = fmaxf(o, 0.f);
        }
    }
}

extern "C" void kernel_launch(void* const* d_in, const int* in_sizes, int n_in,
                              void* d_out, int out_size, void* d_ws, size_t ws_size,
                              hipStream_t stream) {
    const float* pus = (const float*)d_in[2];
    const float* pis = (const float*)d_in[3];
    const float* pss = (const float*)d_in[4];
    const float* C   = (const float*)d_in[5];
    const float* W1  = (const float*)d_in[6];
    const float* b1  = (const float*)d_in[7];
    const float* W2  = (const float*)d_in[8];
    const float* b2  = (const float*)d_in[9];
    const float* WR  = (const float*)d_in[10];
    const float* bR  = (const float*)d_in[11];
    const float* Wo  = (const float*)d_in[12];
    const float* bo  = (const float*)d_in[13];
    (void)in_sizes; (void)n_in; (void)ws_size;

    // workspace: W1t bf16[128*384] | WRt bf16[128*256]
    __bf16* W1t = (__bf16*)d_ws;
    __bf16* WRt = W1t + 384 * 128;

    prep_weights<<<320, 256, 0, stream>>>(W1, WR, W1t, WRt);
    fused<<<M_, 256, 0, stream>>>(pus, pis, pss, C, W1t, b1, W2, b2,
                                  WRt, bR, Wo, bo, (float*)d_out);
}